// Round 12
// baseline (394.870 us; speedup 1.0000x reference)
//
#include <hip/hip_runtime.h>

// SGConv (K=2) on MI355X. XCD-sliced fp16 hops (16 cols/slice, L2-resident) +
// fp16 MFMA GEMM.
// ws layout (78.6MB): counts int[N] @0 ; dinv float[N] @512KB ; gcur @960KB ;
// srcbuf int[N*64] @1MB (25.6MB) ; xh f16[(N+1)*128] @27MB (25.6MB, reused as h2h) ;
// h1 col-sliced f16 [8][(N+1)*16] @53MB (25.6MB, binned u32 7.6MB aliases head;
// h1s sentinels are therefore zeroed INSIDE k_hop<1>, after binned is dead).
#define CAP 64
#define NPB 256
#define NPB_SHIFT 8
#define CAPB 4864
#define EPB 4096
#define MAXB 512
#define BBT 1024  // binB block size (16 waves)

typedef __attribute__((ext_vector_type(8))) _Float16 half8v;
typedef __attribute__((ext_vector_type(2))) _Float16 h2v;
typedef __attribute__((ext_vector_type(4))) float f32x4;

__device__ __forceinline__ unsigned pkh2(float x, float y) {
  h2v h;
  h[0] = (_Float16)x;
  h[1] = (_Float16)y;
  return __builtin_bit_cast(unsigned, h);
}

// ---- phase A: bin edges by target bucket, packed (src<<8 | col&255) ----
__global__ __launch_bounds__(256) void k_binA(const int* __restrict__ row,
                                              const int* __restrict__ col,
                                              int* __restrict__ gcur,
                                              unsigned int* __restrict__ binned,
                                              int E, int nb) {
  __shared__ int lcnt[MAXB];
  int tid = threadIdx.x;
  for (int i = tid; i < nb; i += 256) lcnt[i] = 0;
  __syncthreads();
  int e0 = blockIdx.x * EPB;
#pragma unroll
  for (int it = 0; it < EPB / 256; ++it) {
    int e = e0 + it * 256 + tid;
    if (e < E) atomicAdd(&lcnt[col[e] >> NPB_SHIFT], 1);
  }
  __syncthreads();
  for (int b = tid; b < nb; b += 256) {
    int c = lcnt[b];
    lcnt[b] = (c > 0) ? atomicAdd(&gcur[b], c) : 0;
  }
  __syncthreads();
#pragma unroll
  for (int it = 0; it < EPB / 256; ++it) {
    int e = e0 + it * 256 + tid;
    if (e < E) {
      int c = col[e];
      int s = row[e];
      int b = c >> NPB_SHIFT;
      int pos = atomicAdd(&lcnt[b], 1);
      if (pos < (b + 1) * CAPB)
        binned[pos] = ((unsigned)s << NPB_SHIFT) | (unsigned)(c & (NPB - 1));
    }
  }
}

// ---- phase B (1024 thr): per-bucket LDS ranks; L2-local scatter; self+pad8;
// fused prescale xh = f16(dinv*x) for the bucket's 256 nodes ----
__global__ __launch_bounds__(BBT) void k_binB(const unsigned int* __restrict__ binned,
                                              const int* __restrict__ gcur,
                                              int* __restrict__ counts,
                                              float* __restrict__ dinv,
                                              int* __restrict__ srcbuf,
                                              const float2* __restrict__ x2,
                                              unsigned* __restrict__ xh,
                                              int N) {
  __shared__ int cur[NPB];
  __shared__ float dl[NPB];
  int tid = threadIdx.x;
  int b = blockIdx.x;
  if (tid < NPB) cur[tid] = 0;
  __syncthreads();
  int cnt = gcur[b] - b * CAPB;
  if (cnt > CAPB) cnt = CAPB;
  const unsigned int* bp = binned + (size_t)b * CAPB;
  int nb0 = b << NPB_SHIFT;
  int e = tid;
  for (; e + 3 * BBT < cnt; e += 4 * BBT) {  // 4 loads in flight
    unsigned p0 = bp[e];
    unsigned p1 = bp[e + BBT];
    unsigned p2 = bp[e + 2 * BBT];
    unsigned p3 = bp[e + 3 * BBT];
    int r0 = atomicAdd(&cur[p0 & (NPB - 1)], 1);
    if (r0 < CAP - 1) srcbuf[((size_t)(nb0 + (p0 & (NPB - 1))) << 6) + r0] = (int)(p0 >> NPB_SHIFT);
    int r1 = atomicAdd(&cur[p1 & (NPB - 1)], 1);
    if (r1 < CAP - 1) srcbuf[((size_t)(nb0 + (p1 & (NPB - 1))) << 6) + r1] = (int)(p1 >> NPB_SHIFT);
    int r2 = atomicAdd(&cur[p2 & (NPB - 1)], 1);
    if (r2 < CAP - 1) srcbuf[((size_t)(nb0 + (p2 & (NPB - 1))) << 6) + r2] = (int)(p2 >> NPB_SHIFT);
    int r3 = atomicAdd(&cur[p3 & (NPB - 1)], 1);
    if (r3 < CAP - 1) srcbuf[((size_t)(nb0 + (p3 & (NPB - 1))) << 6) + r3] = (int)(p3 >> NPB_SHIFT);
  }
  for (; e < cnt; e += BBT) {
    unsigned p = bp[e];
    int li = p & (NPB - 1);
    int r = atomicAdd(&cur[li], 1);
    if (r < CAP - 1) srcbuf[((size_t)(nb0 + li) << 6) + r] = (int)(p >> NPB_SHIFT);
  }
  __syncthreads();
  if (tid < NPB) {
    int node = nb0 + tid;
    if (node < N) {
      int c = cur[tid];
      int mlen = (c < CAP - 1) ? c : (CAP - 1);
      int* myp = srcbuf + ((size_t)node << 6);
      myp[mlen] = node;                    // self-loop entry (operand prescaled)
      int cntp = (mlen + 1 + 7) & ~7;      // pad to multiple of 8
      for (int p2 = mlen + 1; p2 < cntp; ++p2) myp[p2] = N;  // sentinel zero row
      counts[node] = cntp;
      float d = rsqrtf((float)c + 1.0f);
      dinv[node] = d;
      dl[tid] = d;
    }
  }
  __syncthreads();
  // fused prescale: 256 nodes x 64 f16-pairs = 16384 elems, 2/thread/iter
#pragma unroll
  for (int it = 0; it < 8; ++it) {
    int idx0 = (it * 2) * BBT + tid;
    int idx1 = (it * 2 + 1) * BBT + tid;
    float2 v0, v1;
    bool ok0 = nb0 + (idx0 >> 6) < N;
    bool ok1 = nb0 + (idx1 >> 6) < N;
    if (ok0) v0 = x2[((size_t)nb0 << 6) + idx0];
    if (ok1) v1 = x2[((size_t)nb0 << 6) + idx1];
    if (ok0) {
      float d = dl[idx0 >> 6];
      xh[((size_t)nb0 << 6) + idx0] = pkh2(v0.x * d, v0.y * d);
    }
    if (ok1) {
      float d = dl[idx1 >> 6];
      xh[((size_t)nb0 << 6) + idx1] = pkh2(v1.x * d, v1.y * d);
    }
  }
}

// ---- init: gcur cursors only (h1s sentinels handled in k_hop<1>) ----
__global__ void k_init(int* __restrict__ gcur, int nb) {
  int i = blockIdx.x * blockDim.x + threadIdx.x;
  if (i < nb) gcur[i] = i * CAPB;
}

// ---- XCD-sliced hop. Block = (bucket, slice): slice = blockIdx&7 pins all
// same-slice blocks to one XCD (round-robin dispatch) -> 3.2MB slice is
// L2-resident. Wave = 4 nodes x 16 lanes (8 edge-subgroups x 2 lanes of
// dwordx4 = 32B slice row). 3-step shfl_xor reduce over subgroups.
// MODE 1: in xh row-major, out h1 col-sliced, scale d^2 (stay pre-scaled);
//         bucket-0 blocks also zero their slice's sentinel row (index n) --
//         safe: no reader of h1s exists during this dispatch.
// MODE 2: in h1 col-sliced, out h2 row-major, scale d. ----
template <int MODE>
__global__ __launch_bounds__(256) void k_hop(
    const unsigned* __restrict__ hin, unsigned* __restrict__ hout,
    const int* __restrict__ srcbuf, const int* __restrict__ counts,
    const float* __restrict__ dinv, int n) {
  int blk = blockIdx.x;
  int slice = blk & 7;
  int bucket = blk >> 3;
  int nb0 = bucket << 8;
  int tid = threadIdx.x;
  int wid = tid >> 6;
  int lane = tid & 63;
  int grp = lane >> 4;        // node within 4-node pack
  int sub = (lane >> 1) & 7;  // edge subgroup
  int m = lane & 1;           // 16B half of the 32B slice row
  const uint4* in4 = (const uint4*)hin;
  uint4* out4 = (uint4*)hout;
  size_t sbase = (size_t)slice * (size_t)(n + 1) * 2;  // uint4 units
  int so2 = slice * 2 + m;

  if (MODE == 1 && bucket == 0 && tid < 2) {
    // zero this slice's sentinel row (binned aliased it until binB finished)
    out4[sbase + (size_t)n * 2 + tid] = make_uint4(0, 0, 0, 0);
  }

  for (int it = 0; it < 16; ++it) {
    int node = nb0 + (wid << 6) + (it << 2) + grp;
    bool ok = node < n;
    int cnt = ok ? counts[node] : 0;
    float di = ok ? dinv[node] : 1.0f;
    const int* sp = srcbuf + ((size_t)node << 6);
    h2v a0 = (h2v)(_Float16)0, a1 = a0, a2 = a0, a3 = a0;
    int e = 0;
    while (__any(e < cnt)) {
      int x = e + sub;
      int src = (x < cnt) ? sp[x] : n;  // sentinel row n is zero
      size_t ii = (MODE == 1) ? ((size_t)src * 16 + so2)
                              : (sbase + (size_t)src * 2 + m);
      uint4 v = in4[ii];
      a0 += __builtin_bit_cast(h2v, v.x);
      a1 += __builtin_bit_cast(h2v, v.y);
      a2 += __builtin_bit_cast(h2v, v.z);
      a3 += __builtin_bit_cast(h2v, v.w);
      e += 8;
    }
    // reduce over the 8 subgroups (lane-space offsets 2,4,8)
#pragma unroll
    for (int off = 2; off <= 8; off <<= 1) {
      a0 += __builtin_bit_cast(h2v, __shfl_xor(__builtin_bit_cast(int, a0), off));
      a1 += __builtin_bit_cast(h2v, __shfl_xor(__builtin_bit_cast(int, a1), off));
      a2 += __builtin_bit_cast(h2v, __shfl_xor(__builtin_bit_cast(int, a2), off));
      a3 += __builtin_bit_cast(h2v, __shfl_xor(__builtin_bit_cast(int, a3), off));
    }
    if ((lane & 14) == 0 && ok) {  // sub==0 lanes (m=0,1)
      _Float16 hs = (_Float16)((MODE == 1) ? di * di : di);
      h2v hv;
      hv[0] = hs;
      hv[1] = hs;
      uint4 o;
      o.x = __builtin_bit_cast(unsigned, (h2v)(a0 * hv));
      o.y = __builtin_bit_cast(unsigned, (h2v)(a1 * hv));
      o.z = __builtin_bit_cast(unsigned, (h2v)(a2 * hv));
      o.w = __builtin_bit_cast(unsigned, (h2v)(a3 * hv));
      size_t oi = (MODE == 1) ? (sbase + (size_t)node * 2 + m)
                              : ((size_t)node * 16 + so2);
      out4[oi] = o;
    }
  }
}

// ---- out = h2h @ W^T + b via mfma_f32_16x16x32_f16 ----
__global__ __launch_bounds__(256) void k_gemm_mfma(
    const unsigned* __restrict__ h2h, const float* __restrict__ W,
    const float* __restrict__ bias, float* __restrict__ out, int n) {
  __shared__ _Float16 Wl[128 * 128];  // 32 KB
  int tid = threadIdx.x;
  const float4* Wg4 = (const float4*)W;
#pragma unroll
  for (int it = 0; it < 8; ++it) {
    int idx = tid + (it << 8);
    int c = idx >> 4;
    int j = idx & 15;
    float4 a = Wg4[c * 32 + j * 2];
    float4 bq = Wg4[c * 32 + j * 2 + 1];
    half8v s;
    s[0] = (_Float16)a.x;  s[1] = (_Float16)a.y;
    s[2] = (_Float16)a.z;  s[3] = (_Float16)a.w;
    s[4] = (_Float16)bq.x; s[5] = (_Float16)bq.y;
    s[6] = (_Float16)bq.z; s[7] = (_Float16)bq.w;
    int eo = (j << 3) ^ ((c & 7) << 3);
    *(half8v*)&Wl[(c << 7) + eo] = s;
  }
  __syncthreads();

  int wv = __builtin_amdgcn_readfirstlane((int)(tid >> 6));
  int lane = tid & 63;
  int tiles = (n + 15) >> 4;
  int tile = blockIdx.x * 4 + wv;
  if (tile >= tiles) return;
  int row0 = tile << 4;
  int r = lane & 15, g = lane >> 4;

  int arow = row0 + r;
  if (arow >= n) arow = n - 1;
  const _Float16* hrow = (const _Float16*)(h2h + ((size_t)arow << 6));
  half8v A0 = *(const half8v*)&hrow[g * 8];
  half8v A1 = *(const half8v*)&hrow[g * 8 + 32];
  half8v A2 = *(const half8v*)&hrow[g * 8 + 64];
  half8v A3 = *(const half8v*)&hrow[g * 8 + 96];

#pragma unroll
  for (int ct = 0; ct < 8; ++ct) {
    int c = (ct << 4) + r;
    int sw = (c & 7) << 3;
    const _Float16* wrow = &Wl[c << 7];
    half8v B0 = *(const half8v*)&wrow[(g * 8) ^ sw];
    half8v B1 = *(const half8v*)&wrow[(g * 8 + 32) ^ sw];
    half8v B2 = *(const half8v*)&wrow[(g * 8 + 64) ^ sw];
    half8v B3 = *(const half8v*)&wrow[(g * 8 + 96) ^ sw];
    f32x4 acc = {0.f, 0.f, 0.f, 0.f};
    acc = __builtin_amdgcn_mfma_f32_16x16x32_f16(A0, B0, acc, 0, 0, 0);
    acc = __builtin_amdgcn_mfma_f32_16x16x32_f16(A1, B1, acc, 0, 0, 0);
    acc = __builtin_amdgcn_mfma_f32_16x16x32_f16(A2, B2, acc, 0, 0, 0);
    acc = __builtin_amdgcn_mfma_f32_16x16x32_f16(A3, B3, acc, 0, 0, 0);
    float bb = bias[c];
#pragma unroll
    for (int q = 0; q < 4; ++q) {
      int rr = row0 + g * 4 + q;
      if (rr < n) out[(size_t)rr * 128 + c] = acc[q] + bb;
    }
  }
}

extern "C" void kernel_launch(void* const* d_in, const int* in_sizes, int n_in,
                              void* d_out, int out_size, void* d_ws, size_t ws_size,
                              hipStream_t stream) {
  const float* x = (const float*)d_in[0];
  const int* ei = (const int*)d_in[1];
  const float* W = (const float*)d_in[2];
  const float* b = (const float*)d_in[3];
  int N = in_sizes[0] / 128;
  int E = in_sizes[1] / 2;
  float* out = (float*)d_out;

  char* ws = (char*)d_ws;
  int* counts = (int*)ws;
  float* dinv = (float*)(ws + (512u << 10));
  int* gcur = (int*)(ws + (960u << 10));
  int* srcbuf = (int*)(ws + (1u << 20));
  unsigned* xh = (unsigned*)(ws + (27u << 20));
  unsigned* h2h = xh;  // xh dead after hop1; reuse for hop2 output
  unsigned* h1s = (unsigned*)(ws + (53u << 20));  // col-sliced [8][(N+1)*16B]
  unsigned int* binned = (unsigned int*)(ws + (53u << 20));  // dead before hop1

  int nb = (N + NPB - 1) >> NPB_SHIFT;
  int blocksA = (E + EPB - 1) / EPB;
  int tiles = (N + 15) >> 4;

  // zero the row-major sentinel row (index N) in xh
  hipMemsetAsync(xh + ((size_t)N << 6), 0, 256, stream);

  k_init<<<(nb + 255) / 256, 256, 0, stream>>>(gcur, nb);
  k_binA<<<blocksA, 256, 0, stream>>>(ei, ei + E, gcur, binned, E, nb);
  k_binB<<<nb, BBT, 0, stream>>>(binned, gcur, counts, dinv, srcbuf,
                                 (const float2*)x, xh, N);
  k_hop<1><<<nb * 8, 256, 0, stream>>>(xh, h1s, srcbuf, counts, dinv, N);
  k_hop<2><<<nb * 8, 256, 0, stream>>>(h1s, h2h, srcbuf, counts, dinv, N);
  k_gemm_mfma<<<(tiles + 3) / 4, 256, 0, stream>>>(h2h, W, b, out, N);
}

// Round 13
// 201.634 us; speedup vs baseline: 1.9583x; 1.9583x over previous
//
#include <hip/hip_runtime.h>

// SGConv (K=2) on MI355X. fp16 hops (packed v_pk_add_f16 accumulate) + fp16 MFMA GEMM.
// ws layout (78.6MB): counts int[N] @0 ; dinv float[N] @512KB ; gcur @960KB ;
// srcbuf int[N*64] @1MB (25.6MB) ; xh f16[(N+1)*128] @27MB (25.6MB, reused as h2h) ;
// h1h f16[(N+1)*128] @53MB (25.6MB; binned u32 7.6MB aliases its HEAD — the
// sentinel row at +25.6MB does not overlap binned).
#define CAP 64
#define NPB 256
#define NPB_SHIFT 8
#define CAPB 4864
#define EPB 4096
#define MAXB 512
#define BBT 1024  // binB block size (16 waves)

typedef __attribute__((ext_vector_type(8))) _Float16 half8v;
typedef __attribute__((ext_vector_type(2))) _Float16 h2v;
typedef __attribute__((ext_vector_type(4))) float f32x4;

__device__ __forceinline__ unsigned pkh2(float x, float y) {
  h2v h;
  h[0] = (_Float16)x;
  h[1] = (_Float16)y;
  return __builtin_bit_cast(unsigned, h);
}

// ---- phase A: bin edges by target bucket, packed (src<<8 | col&255).
// gcur starts at 0; reservation adds b*CAPB (replaces the old k_init). ----
__global__ __launch_bounds__(256) void k_binA(const int* __restrict__ row,
                                              const int* __restrict__ col,
                                              int* __restrict__ gcur,
                                              unsigned int* __restrict__ binned,
                                              int E, int nb) {
  __shared__ int lcnt[MAXB];
  int tid = threadIdx.x;
  for (int i = tid; i < nb; i += 256) lcnt[i] = 0;
  __syncthreads();
  int e0 = blockIdx.x * EPB;
#pragma unroll
  for (int it = 0; it < EPB / 256; ++it) {
    int e = e0 + it * 256 + tid;
    if (e < E) atomicAdd(&lcnt[col[e] >> NPB_SHIFT], 1);
  }
  __syncthreads();
  for (int b = tid; b < nb; b += 256) {
    int c = lcnt[b];
    lcnt[b] = (c > 0) ? atomicAdd(&gcur[b], c) + b * CAPB : 0;
  }
  __syncthreads();
#pragma unroll
  for (int it = 0; it < EPB / 256; ++it) {
    int e = e0 + it * 256 + tid;
    if (e < E) {
      int c = col[e];
      int s = row[e];
      int b = c >> NPB_SHIFT;
      int pos = atomicAdd(&lcnt[b], 1);
      if (pos < (b + 1) * CAPB)
        binned[pos] = ((unsigned)s << NPB_SHIFT) | (unsigned)(c & (NPB - 1));
    }
  }
}

// ---- phase B (1024 thr): per-bucket LDS ranks; L2-local scatter; self+pad8;
// fused prescale xh = f16(dinv*x) for the bucket's 256 nodes ----
__global__ __launch_bounds__(BBT) void k_binB(const unsigned int* __restrict__ binned,
                                              const int* __restrict__ gcur,
                                              int* __restrict__ counts,
                                              float* __restrict__ dinv,
                                              int* __restrict__ srcbuf,
                                              const float2* __restrict__ x2,
                                              unsigned* __restrict__ xh,
                                              int N) {
  __shared__ int cur[NPB];
  __shared__ float dl[NPB];
  int tid = threadIdx.x;
  int b = blockIdx.x;
  if (tid < NPB) cur[tid] = 0;
  __syncthreads();
  int cnt = gcur[b];
  if (cnt > CAPB) cnt = CAPB;
  const unsigned int* bp = binned + (size_t)b * CAPB;
  int nb0 = b << NPB_SHIFT;
  int e = tid;
  for (; e + 3 * BBT < cnt; e += 4 * BBT) {  // 4 loads in flight
    unsigned p0 = bp[e];
    unsigned p1 = bp[e + BBT];
    unsigned p2 = bp[e + 2 * BBT];
    unsigned p3 = bp[e + 3 * BBT];
    int r0 = atomicAdd(&cur[p0 & (NPB - 1)], 1);
    if (r0 < CAP - 1) srcbuf[((size_t)(nb0 + (p0 & (NPB - 1))) << 6) + r0] = (int)(p0 >> NPB_SHIFT);
    int r1 = atomicAdd(&cur[p1 & (NPB - 1)], 1);
    if (r1 < CAP - 1) srcbuf[((size_t)(nb0 + (p1 & (NPB - 1))) << 6) + r1] = (int)(p1 >> NPB_SHIFT);
    int r2 = atomicAdd(&cur[p2 & (NPB - 1)], 1);
    if (r2 < CAP - 1) srcbuf[((size_t)(nb0 + (p2 & (NPB - 1))) << 6) + r2] = (int)(p2 >> NPB_SHIFT);
    int r3 = atomicAdd(&cur[p3 & (NPB - 1)], 1);
    if (r3 < CAP - 1) srcbuf[((size_t)(nb0 + (p3 & (NPB - 1))) << 6) + r3] = (int)(p3 >> NPB_SHIFT);
  }
  for (; e < cnt; e += BBT) {
    unsigned p = bp[e];
    int li = p & (NPB - 1);
    int r = atomicAdd(&cur[li], 1);
    if (r < CAP - 1) srcbuf[((size_t)(nb0 + li) << 6) + r] = (int)(p >> NPB_SHIFT);
  }
  __syncthreads();
  if (tid < NPB) {
    int node = nb0 + tid;
    if (node < N) {
      int c = cur[tid];
      int mlen = (c < CAP - 1) ? c : (CAP - 1);
      int* myp = srcbuf + ((size_t)node << 6);
      myp[mlen] = node;                    // self-loop entry (operand prescaled)
      int cntp = (mlen + 1 + 7) & ~7;      // pad to multiple of 8
      for (int p2 = mlen + 1; p2 < cntp; ++p2) myp[p2] = N;  // sentinel zero row
      counts[node] = cntp;
      float d = rsqrtf((float)c + 1.0f);
      dinv[node] = d;
      dl[tid] = d;
    }
  }
  __syncthreads();
  // fused prescale: 256 nodes x 64 f16-pairs = 16384 elems, 2/thread/iter
#pragma unroll
  for (int it = 0; it < 8; ++it) {
    int idx0 = (it * 2) * BBT + tid;
    int idx1 = (it * 2 + 1) * BBT + tid;
    float2 v0, v1;
    bool ok0 = nb0 + (idx0 >> 6) < N;
    bool ok1 = nb0 + (idx1 >> 6) < N;
    if (ok0) v0 = x2[((size_t)nb0 << 6) + idx0];
    if (ok1) v1 = x2[((size_t)nb0 << 6) + idx1];
    if (ok0) {
      float d = dl[idx0 >> 6];
      xh[((size_t)nb0 << 6) + idx0] = pkh2(v0.x * d, v0.y * d);
    }
    if (ok1) {
      float d = dl[idx1 >> 6];
      xh[((size_t)nb0 << 6) + idx1] = pkh2(v1.x * d, v1.y * d);
    }
  }
}

// ---- hop: S[node] = sum over padded src list (incl self) of f16 rows.
// dwordx4 gathers: 16-lane subgroup g covers one edge; lane m owns 16B
// (8 f16 cols). Accumulate PACKED via v_pk_add_f16: 4 VALU per uint4.
// MODE 1: write f16(d^2*S) (stay pre-scaled). MODE 2: write f16(d*S). ----
#define PACC(v)                                   \
  A[0] += __builtin_bit_cast(h2v, (v).x);         \
  A[1] += __builtin_bit_cast(h2v, (v).y);         \
  A[2] += __builtin_bit_cast(h2v, (v).z);         \
  A[3] += __builtin_bit_cast(h2v, (v).w);

template <int MODE>
__global__ __launch_bounds__(256) void k_hop(
    const unsigned* __restrict__ hin, unsigned* __restrict__ hout,
    const int* __restrict__ srcbuf, const int* __restrict__ counts,
    const float* __restrict__ dinv, int n) {
  int wave = __builtin_amdgcn_readfirstlane((int)(threadIdx.x >> 6));
  int lane = threadIdx.x & 63;
  int node = blockIdx.x * 4 + wave;
  if (node >= n) return;
  int cntp = counts[node];  // multiple of 8, >= 8 (self always present)
  float di = dinv[node];
  int g = lane >> 4;
  int m = lane & 15;
  const uint4* h4 = (const uint4*)hin;
  const int* sp = srcbuf + ((size_t)node << 6);
  h2v A[4];
#pragma unroll
  for (int q = 0; q < 4; ++q) A[q] = (h2v)(_Float16)0;
  int e = 0;
  for (; e + 16 <= cntp; e += 16) {
    int s0 = sp[e + g];
    int s1 = sp[e + 4 + g];
    int s2 = sp[e + 8 + g];
    int s3 = sp[e + 12 + g];
    uint4 v0 = h4[((size_t)s0 << 4) + m];
    uint4 v1 = h4[((size_t)s1 << 4) + m];
    uint4 v2 = h4[((size_t)s2 << 4) + m];
    uint4 v3 = h4[((size_t)s3 << 4) + m];
    PACC(v0); PACC(v1); PACC(v2); PACC(v3);
  }
  if (e < cntp) {  // exactly 8 remain
    int s0 = sp[e + g];
    int s1 = sp[e + 4 + g];
    uint4 v0 = h4[((size_t)s0 << 4) + m];
    uint4 v1 = h4[((size_t)s1 << 4) + m];
    PACC(v0); PACC(v1);
  }
  // combine the 4 edge-subgroups (packed adds through shfl)
#pragma unroll
  for (int q = 0; q < 4; ++q) {
    A[q] += __builtin_bit_cast(h2v, __shfl_xor(__builtin_bit_cast(int, A[q]), 32));
    A[q] += __builtin_bit_cast(h2v, __shfl_xor(__builtin_bit_cast(int, A[q]), 16));
  }
  float s = (MODE == 1) ? di * di : di;
  if (g == 0) {
    uint4 o;
    o.x = pkh2((float)A[0][0] * s, (float)A[0][1] * s);
    o.y = pkh2((float)A[1][0] * s, (float)A[1][1] * s);
    o.z = pkh2((float)A[2][0] * s, (float)A[2][1] * s);
    o.w = pkh2((float)A[3][0] * s, (float)A[3][1] * s);
    *(uint4*)&hout[((size_t)node << 6) + (m << 2)] = o;  // 16 lanes x 16B = row
  }
}

// ---- out = h2h @ W^T + b via mfma_f32_16x16x32_f16.
// Wave = one 16-row tile. A frag: row=lane&15, k=(lane>>4)*8+i. W cvt to f16
// in LDS, per-row XOR swizzle -> conflict-free broadcast reads.
// C/D: col=lane&15, row=(lane>>4)*4+reg (dtype-independent). ----
__global__ __launch_bounds__(256) void k_gemm_mfma(
    const unsigned* __restrict__ h2h, const float* __restrict__ W,
    const float* __restrict__ bias, float* __restrict__ out, int n) {
  __shared__ _Float16 Wl[128 * 128];  // 32 KB
  int tid = threadIdx.x;
  const float4* Wg4 = (const float4*)W;
#pragma unroll
  for (int it = 0; it < 8; ++it) {
    int idx = tid + (it << 8);
    int c = idx >> 4;
    int j = idx & 15;
    float4 a = Wg4[c * 32 + j * 2];
    float4 bq = Wg4[c * 32 + j * 2 + 1];
    half8v s;
    s[0] = (_Float16)a.x;  s[1] = (_Float16)a.y;
    s[2] = (_Float16)a.z;  s[3] = (_Float16)a.w;
    s[4] = (_Float16)bq.x; s[5] = (_Float16)bq.y;
    s[6] = (_Float16)bq.z; s[7] = (_Float16)bq.w;
    int eo = (j << 3) ^ ((c & 7) << 3);
    *(half8v*)&Wl[(c << 7) + eo] = s;
  }
  __syncthreads();

  int wv = __builtin_amdgcn_readfirstlane((int)(tid >> 6));
  int lane = tid & 63;
  int tiles = (n + 15) >> 4;
  int tile = blockIdx.x * 4 + wv;
  if (tile >= tiles) return;
  int row0 = tile << 4;
  int r = lane & 15, g = lane >> 4;

  int arow = row0 + r;
  if (arow >= n) arow = n - 1;
  const _Float16* hrow = (const _Float16*)(h2h + ((size_t)arow << 6));
  half8v A0 = *(const half8v*)&hrow[g * 8];
  half8v A1 = *(const half8v*)&hrow[g * 8 + 32];
  half8v A2 = *(const half8v*)&hrow[g * 8 + 64];
  half8v A3 = *(const half8v*)&hrow[g * 8 + 96];

#pragma unroll
  for (int ct = 0; ct < 8; ++ct) {
    int c = (ct << 4) + r;
    int sw = (c & 7) << 3;
    const _Float16* wrow = &Wl[c << 7];
    half8v B0 = *(const half8v*)&wrow[(g * 8) ^ sw];
    half8v B1 = *(const half8v*)&wrow[(g * 8 + 32) ^ sw];
    half8v B2 = *(const half8v*)&wrow[(g * 8 + 64) ^ sw];
    half8v B3 = *(const half8v*)&wrow[(g * 8 + 96) ^ sw];
    f32x4 acc = {0.f, 0.f, 0.f, 0.f};
    acc = __builtin_amdgcn_mfma_f32_16x16x32_f16(A0, B0, acc, 0, 0, 0);
    acc = __builtin_amdgcn_mfma_f32_16x16x32_f16(A1, B1, acc, 0, 0, 0);
    acc = __builtin_amdgcn_mfma_f32_16x16x32_f16(A2, B2, acc, 0, 0, 0);
    acc = __builtin_amdgcn_mfma_f32_16x16x32_f16(A3, B3, acc, 0, 0, 0);
    float bb = bias[c];
#pragma unroll
    for (int q = 0; q < 4; ++q) {
      int rr = row0 + g * 4 + q;
      if (rr < n) out[(size_t)rr * 128 + c] = acc[q] + bb;
    }
  }
}

extern "C" void kernel_launch(void* const* d_in, const int* in_sizes, int n_in,
                              void* d_out, int out_size, void* d_ws, size_t ws_size,
                              hipStream_t stream) {
  const float* x = (const float*)d_in[0];
  const int* ei = (const int*)d_in[1];
  const float* W = (const float*)d_in[2];
  const float* b = (const float*)d_in[3];
  int N = in_sizes[0] / 128;
  int E = in_sizes[1] / 2;
  float* out = (float*)d_out;

  char* ws = (char*)d_ws;
  int* counts = (int*)ws;
  float* dinv = (float*)(ws + (512u << 10));
  int* gcur = (int*)(ws + (960u << 10));
  int* srcbuf = (int*)(ws + (1u << 20));
  unsigned* xh = (unsigned*)(ws + (27u << 20));
  unsigned* h2h = xh;  // xh dead after hop1; reuse for hop2 output
  unsigned* h1h = (unsigned*)(ws + (53u << 20));
  unsigned int* binned = (unsigned int*)(ws + (53u << 20));  // dead before hop1

  int nb = (N + NPB - 1) >> NPB_SHIFT;
  int blocksA = (E + EPB - 1) / EPB;
  int tiles = (N + 15) >> 4;

  // zero gcur cursors + the sentinel rows (index N) in both f16 buffers
  hipMemsetAsync(gcur, 0, nb * sizeof(int), stream);
  hipMemsetAsync(xh + ((size_t)N << 6), 0, 256, stream);
  hipMemsetAsync(h1h + ((size_t)N << 6), 0, 256, stream);

  k_binA<<<blocksA, 256, 0, stream>>>(ei, ei + E, gcur, binned, E, nb);
  k_binB<<<nb, BBT, 0, stream>>>(binned, gcur, counts, dinv, srcbuf,
                                 (const float2*)x, xh, N);
  k_hop<1><<<(N + 3) / 4, 256, 0, stream>>>(xh, h1h, srcbuf, counts, dinv, N);
  k_hop<2><<<(N + 3) / 4, 256, 0, stream>>>(h1h, h2h, srcbuf, counts, dinv, N);
  k_gemm_mfma<<<(tiles + 3) / 4, 256, 0, stream>>>(h2h, W, b, out, N);
}

// Round 14
// 191.906 us; speedup vs baseline: 2.0576x; 1.0507x over previous
//
#include <hip/hip_runtime.h>

// SGConv (K=2) on MI355X. fp16 hops (packed v_pk_add_f16 accumulate) + fp16 MFMA GEMM.
// ws layout (78.6MB): counts int[N] @0 ; dinv float[N] @512KB ; gcur @960KB ;
// srcbuf int[N*64] @1MB (25.6MB) ; xh f16[(N+1)*128] @27MB (25.6MB, reused as h2h) ;
// h1h f16[(N+1)*128] @53MB (25.6MB; binned u32 7.6MB aliases its HEAD — the
// sentinel row at +25.6MB does not overlap binned).
#define CAP 64
#define NPB 256
#define NPB_SHIFT 8
#define CAPB 4864
#define EPB 4096
#define MAXB 512
#define BBT 1024  // binB block size (16 waves)

typedef __attribute__((ext_vector_type(8))) _Float16 half8v;
typedef __attribute__((ext_vector_type(2))) _Float16 h2v;
typedef __attribute__((ext_vector_type(4))) float f32x4;

__device__ __forceinline__ unsigned pkh2(float x, float y) {
  h2v h;
  h[0] = (_Float16)x;
  h[1] = (_Float16)y;
  return __builtin_bit_cast(unsigned, h);
}

// ---- phase A: bin edges by target bucket, packed (src<<8 | col&255).
// Single col read (kept in regs across hist->scatter). Block 0 also zeroes
// the xh/h1h sentinel rows (safe: binA precedes all their readers/writers,
// and the sentinels do not overlap binned). ----
__global__ __launch_bounds__(256) void k_binA(const int* __restrict__ row,
                                              const int* __restrict__ col,
                                              int* __restrict__ gcur,
                                              unsigned int* __restrict__ binned,
                                              unsigned* __restrict__ xh,
                                              unsigned* __restrict__ h1h,
                                              int E, int nb, int N) {
  __shared__ int lcnt[MAXB];
  int tid = threadIdx.x;
  for (int i = tid; i < nb; i += 256) lcnt[i] = 0;
  if (blockIdx.x == 0 && tid < 64) {  // zero sentinel rows (64 u32 each)
    xh[((size_t)N << 6) + tid] = 0;
    h1h[((size_t)N << 6) + tid] = 0;
  }
  __syncthreads();
  int e0 = blockIdx.x * EPB;
  int creg[16];
#pragma unroll
  for (int it = 0; it < 16; ++it) {
    int e = e0 + it * 256 + tid;
    creg[it] = (e < E) ? col[e] : -1;
  }
#pragma unroll
  for (int it = 0; it < 16; ++it) {
    if (creg[it] >= 0) atomicAdd(&lcnt[creg[it] >> NPB_SHIFT], 1);
  }
  __syncthreads();
  for (int b = tid; b < nb; b += 256) {
    int c = lcnt[b];
    lcnt[b] = (c > 0) ? atomicAdd(&gcur[b], c) + b * CAPB : 0;
  }
  __syncthreads();
#pragma unroll
  for (int it = 0; it < 16; ++it) {
    int e = e0 + it * 256 + tid;
    if (e < E) {
      int c = creg[it];
      int s = row[e];
      int b = c >> NPB_SHIFT;
      int pos = atomicAdd(&lcnt[b], 1);
      if (pos < (b + 1) * CAPB)
        binned[pos] = ((unsigned)s << NPB_SHIFT) | (unsigned)(c & (NPB - 1));
    }
  }
}

// ---- phase B (1024 thr): per-bucket LDS ranks; L2-local scatter (uint4 index
// reads); self+pad8; fused prescale xh = f16(dinv*x) (float4 in / uint2 out) ----
__global__ __launch_bounds__(BBT) void k_binB(const unsigned int* __restrict__ binned,
                                              const int* __restrict__ gcur,
                                              int* __restrict__ counts,
                                              float* __restrict__ dinv,
                                              int* __restrict__ srcbuf,
                                              const float4* __restrict__ x4,
                                              unsigned* __restrict__ xh,
                                              int N) {
  __shared__ int cur[NPB];
  __shared__ float dl[NPB];
  int tid = threadIdx.x;
  int b = blockIdx.x;
  if (tid < NPB) cur[tid] = 0;
  __syncthreads();
  int cnt = gcur[b];
  if (cnt > CAPB) cnt = CAPB;
  const unsigned int* bp = binned + (size_t)b * CAPB;
  int nb0 = b << NPB_SHIFT;
#define BPROC(pv)                                                          \
  {                                                                        \
    int li_ = (int)((pv) & (NPB - 1));                                     \
    int r_ = atomicAdd(&cur[li_], 1);                                      \
    if (r_ < CAP - 1)                                                      \
      srcbuf[((size_t)(nb0 + li_) << 6) + r_] = (int)((pv) >> NPB_SHIFT);  \
  }
  int nv = cnt >> 2;  // full uint4 groups (CAPB%4==0 so bp is 16B-aligned)
  const uint4* bp4 = (const uint4*)bp;
  for (int i = tid; i < nv; i += BBT) {
    uint4 p = bp4[i];
    BPROC(p.x); BPROC(p.y); BPROC(p.z); BPROC(p.w);
  }
  for (int e = (nv << 2) + tid; e < cnt; e += BBT) BPROC(bp[e]);
#undef BPROC
  __syncthreads();
  if (tid < NPB) {
    int node = nb0 + tid;
    if (node < N) {
      int c = cur[tid];
      int mlen = (c < CAP - 1) ? c : (CAP - 1);
      int* myp = srcbuf + ((size_t)node << 6);
      myp[mlen] = node;                    // self-loop entry (operand prescaled)
      int cntp = (mlen + 1 + 7) & ~7;      // pad to multiple of 8
      for (int p2 = mlen + 1; p2 < cntp; ++p2) myp[p2] = N;  // sentinel zero row
      counts[node] = cntp;
      float d = rsqrtf((float)c + 1.0f);
      dinv[node] = d;
      dl[tid] = d;
    }
  }
  __syncthreads();
  // fused prescale: 256 nodes x 32 float4 = 8192 float4s, 1/thread/iter
  uint2* xh2 = (uint2*)xh;
#pragma unroll
  for (int it = 0; it < 8; ++it) {
    int idx = it * BBT + tid;  // 0..8191
    int ln = idx >> 5;         // 32 float4 per row
    if (nb0 + ln < N) {
      float4 v = x4[((size_t)nb0 << 5) + idx];
      float d = dl[ln];
      uint2 o;
      o.x = pkh2(v.x * d, v.y * d);
      o.y = pkh2(v.z * d, v.w * d);
      xh2[((size_t)nb0 << 5) + idx] = o;
    }
  }
}

// ---- hop: S[node] = sum over padded src list (incl self) of f16 rows.
// dwordx4 gathers: 16-lane subgroup g covers one edge; lane m owns 16B
// (8 f16 cols). Accumulate PACKED via v_pk_add_f16: 4 VALU per uint4.
// MODE 1: write f16(d^2*S) (stay pre-scaled). MODE 2: write f16(d*S). ----
#define PACC(v)                                   \
  A[0] += __builtin_bit_cast(h2v, (v).x);         \
  A[1] += __builtin_bit_cast(h2v, (v).y);         \
  A[2] += __builtin_bit_cast(h2v, (v).z);         \
  A[3] += __builtin_bit_cast(h2v, (v).w);

template <int MODE>
__global__ __launch_bounds__(256) void k_hop(
    const unsigned* __restrict__ hin, unsigned* __restrict__ hout,
    const int* __restrict__ srcbuf, const int* __restrict__ counts,
    const float* __restrict__ dinv, int n) {
  int wave = __builtin_amdgcn_readfirstlane((int)(threadIdx.x >> 6));
  int lane = threadIdx.x & 63;
  int node = blockIdx.x * 4 + wave;
  if (node >= n) return;
  int cntp = counts[node];  // multiple of 8, >= 8 (self always present)
  float di = dinv[node];
  int g = lane >> 4;
  int m = lane & 15;
  const uint4* h4 = (const uint4*)hin;
  const int* sp = srcbuf + ((size_t)node << 6);
  h2v A[4];
#pragma unroll
  for (int q = 0; q < 4; ++q) A[q] = (h2v)(_Float16)0;
  int e = 0;
  for (; e + 16 <= cntp; e += 16) {
    int s0 = sp[e + g];
    int s1 = sp[e + 4 + g];
    int s2 = sp[e + 8 + g];
    int s3 = sp[e + 12 + g];
    uint4 v0 = h4[((size_t)s0 << 4) + m];
    uint4 v1 = h4[((size_t)s1 << 4) + m];
    uint4 v2 = h4[((size_t)s2 << 4) + m];
    uint4 v3 = h4[((size_t)s3 << 4) + m];
    PACC(v0); PACC(v1); PACC(v2); PACC(v3);
  }
  if (e < cntp) {  // exactly 8 remain
    int s0 = sp[e + g];
    int s1 = sp[e + 4 + g];
    uint4 v0 = h4[((size_t)s0 << 4) + m];
    uint4 v1 = h4[((size_t)s1 << 4) + m];
    PACC(v0); PACC(v1);
  }
  // combine the 4 edge-subgroups (packed adds through shfl)
#pragma unroll
  for (int q = 0; q < 4; ++q) {
    A[q] += __builtin_bit_cast(h2v, __shfl_xor(__builtin_bit_cast(int, A[q]), 32));
    A[q] += __builtin_bit_cast(h2v, __shfl_xor(__builtin_bit_cast(int, A[q]), 16));
  }
  float s = (MODE == 1) ? di * di : di;
  if (g == 0) {
    uint4 o;
    o.x = pkh2((float)A[0][0] * s, (float)A[0][1] * s);
    o.y = pkh2((float)A[1][0] * s, (float)A[1][1] * s);
    o.z = pkh2((float)A[2][0] * s, (float)A[2][1] * s);
    o.w = pkh2((float)A[3][0] * s, (float)A[3][1] * s);
    *(uint4*)&hout[((size_t)node << 6) + (m << 2)] = o;  // 16 lanes x 16B = row
  }
}

// ---- out = h2h @ W^T + b via mfma_f32_16x16x32_f16.
// Wave = one 16-row tile. A frag: row=lane&15, k=(lane>>4)*8+i. W cvt to f16
// in LDS, per-row XOR swizzle -> conflict-free broadcast reads.
// C/D: col=lane&15, row=(lane>>4)*4+reg (dtype-independent). ----
__global__ __launch_bounds__(256) void k_gemm_mfma(
    const unsigned* __restrict__ h2h, const float* __restrict__ W,
    const float* __restrict__ bias, float* __restrict__ out, int n) {
  __shared__ _Float16 Wl[128 * 128];  // 32 KB
  int tid = threadIdx.x;
  const float4* Wg4 = (const float4*)W;
#pragma unroll
  for (int it = 0; it < 8; ++it) {
    int idx = tid + (it << 8);
    int c = idx >> 4;
    int j = idx & 15;
    float4 a = Wg4[c * 32 + j * 2];
    float4 bq = Wg4[c * 32 + j * 2 + 1];
    half8v s;
    s[0] = (_Float16)a.x;  s[1] = (_Float16)a.y;
    s[2] = (_Float16)a.z;  s[3] = (_Float16)a.w;
    s[4] = (_Float16)bq.x; s[5] = (_Float16)bq.y;
    s[6] = (_Float16)bq.z; s[7] = (_Float16)bq.w;
    int eo = (j << 3) ^ ((c & 7) << 3);
    *(half8v*)&Wl[(c << 7) + eo] = s;
  }
  __syncthreads();

  int wv = __builtin_amdgcn_readfirstlane((int)(tid >> 6));
  int lane = tid & 63;
  int tiles = (n + 15) >> 4;
  int tile = blockIdx.x * 4 + wv;
  if (tile >= tiles) return;
  int row0 = tile << 4;
  int r = lane & 15, g = lane >> 4;

  int arow = row0 + r;
  if (arow >= n) arow = n - 1;
  const _Float16* hrow = (const _Float16*)(h2h + ((size_t)arow << 6));
  half8v A0 = *(const half8v*)&hrow[g * 8];
  half8v A1 = *(const half8v*)&hrow[g * 8 + 32];
  half8v A2 = *(const half8v*)&hrow[g * 8 + 64];
  half8v A3 = *(const half8v*)&hrow[g * 8 + 96];

#pragma unroll
  for (int ct = 0; ct < 8; ++ct) {
    int c = (ct << 4) + r;
    int sw = (c & 7) << 3;
    const _Float16* wrow = &Wl[c << 7];
    half8v B0 = *(const half8v*)&wrow[(g * 8) ^ sw];
    half8v B1 = *(const half8v*)&wrow[(g * 8 + 32) ^ sw];
    half8v B2 = *(const half8v*)&wrow[(g * 8 + 64) ^ sw];
    half8v B3 = *(const half8v*)&wrow[(g * 8 + 96) ^ sw];
    f32x4 acc = {0.f, 0.f, 0.f, 0.f};
    acc = __builtin_amdgcn_mfma_f32_16x16x32_f16(A0, B0, acc, 0, 0, 0);
    acc = __builtin_amdgcn_mfma_f32_16x16x32_f16(A1, B1, acc, 0, 0, 0);
    acc = __builtin_amdgcn_mfma_f32_16x16x32_f16(A2, B2, acc, 0, 0, 0);
    acc = __builtin_amdgcn_mfma_f32_16x16x32_f16(A3, B3, acc, 0, 0, 0);
    float bb = bias[c];
#pragma unroll
    for (int q = 0; q < 4; ++q) {
      int rr = row0 + g * 4 + q;
      if (rr < n) out[(size_t)rr * 128 + c] = acc[q] + bb;
    }
  }
}

extern "C" void kernel_launch(void* const* d_in, const int* in_sizes, int n_in,
                              void* d_out, int out_size, void* d_ws, size_t ws_size,
                              hipStream_t stream) {
  const float* x = (const float*)d_in[0];
  const int* ei = (const int*)d_in[1];
  const float* W = (const float*)d_in[2];
  const float* b = (const float*)d_in[3];
  int N = in_sizes[0] / 128;
  int E = in_sizes[1] / 2;
  float* out = (float*)d_out;

  char* ws = (char*)d_ws;
  int* counts = (int*)ws;
  float* dinv = (float*)(ws + (512u << 10));
  int* gcur = (int*)(ws + (960u << 10));
  int* srcbuf = (int*)(ws + (1u << 20));
  unsigned* xh = (unsigned*)(ws + (27u << 20));
  unsigned* h2h = xh;  // xh dead after hop1; reuse for hop2 output
  unsigned* h1h = (unsigned*)(ws + (53u << 20));
  unsigned int* binned = (unsigned int*)(ws + (53u << 20));  // dead before hop1

  int nb = (N + NPB - 1) >> NPB_SHIFT;
  int blocksA = (E + EPB - 1) / EPB;
  int tiles = (N + 15) >> 4;

  hipMemsetAsync(gcur, 0, nb * sizeof(int), stream);
  k_binA<<<blocksA, 256, 0, stream>>>(ei, ei + E, gcur, binned, xh, h1h, E, nb, N);
  k_binB<<<nb, BBT, 0, stream>>>(binned, gcur, counts, dinv, srcbuf,
                                 (const float4*)x, xh, N);
  k_hop<1><<<(N + 3) / 4, 256, 0, stream>>>(xh, h1h, srcbuf, counts, dinv, N);
  k_hop<2><<<(N + 3) / 4, 256, 0, stream>>>(h1h, h2h, srcbuf, counts, dinv, N);
  k_gemm_mfma<<<(tiles + 3) / 4, 256, 0, stream>>>(h2h, W, b, out, N);
}

// Round 15
// 191.111 us; speedup vs baseline: 2.0662x; 1.0042x over previous
//
#include <hip/hip_runtime.h>

// SGConv (K=2) on MI355X. fp16 hops (packed v_pk_add_f16 accumulate) + fp16 MFMA GEMM.
// ws layout (78.6MB): counts int[N] @0 ; dinv float[N] @512KB ; gcur @960KB ;
// srcbuf int[N*64] @1MB (25.6MB) ; xh f16[(N+1)*128] @27MB (25.6MB, reused as h2h) ;
// h1h f16[(N+1)*128] @53MB (25.6MB; binned u32 7.6MB aliases its HEAD — the
// sentinel row at +25.6MB does not overlap binned).
#define CAP 64
#define NPB 256
#define NPB_SHIFT 8
#define CAPB 4864
#define EPB 4096
#define MAXB 512
#define BBT 1024  // binB block size (16 waves)

typedef __attribute__((ext_vector_type(8))) _Float16 half8v;
typedef __attribute__((ext_vector_type(2))) _Float16 h2v;
typedef __attribute__((ext_vector_type(4))) float f32x4;

__device__ __forceinline__ unsigned pkh2(float x, float y) {
  h2v h;
  h[0] = (_Float16)x;
  h[1] = (_Float16)y;
  return __builtin_bit_cast(unsigned, h);
}

// ---- phase A: bin edges by target bucket, packed (src<<8 | col&255).
// Block-local counting sort: hist -> global reservation -> exclusive scan ->
// LDS-staged (entry, addr) -> emission in sorted address order (bucket bases
// b*CAPB+off are monotone in b) => ~full-line coalesced binned writes.
// Block 0 also zeroes the xh/h1h sentinel rows. ----
__global__ __launch_bounds__(256) void k_binA(const int* __restrict__ row,
                                              const int* __restrict__ col,
                                              int* __restrict__ gcur,
                                              unsigned int* __restrict__ binned,
                                              unsigned* __restrict__ xh,
                                              unsigned* __restrict__ h1h,
                                              int E, int nb, int N) {
  __shared__ int lcnt[MAXB];   // counts -> exclusive prefix (lstart)
  __shared__ int lbase[MAXB];  // global reserved base per bucket
  __shared__ int lcur[MAXB];   // scatter cursors
  __shared__ unsigned eLDS[EPB];
  __shared__ unsigned aLDS[EPB];
  int tid = threadIdx.x;
  for (int i = tid; i < MAXB; i += 256) lcnt[i] = 0;
  if (blockIdx.x == 0 && tid < 64) {  // zero sentinel rows (64 u32 each)
    xh[((size_t)N << 6) + tid] = 0;
    h1h[((size_t)N << 6) + tid] = 0;
  }
  __syncthreads();
  int e0 = blockIdx.x * EPB;
  int eib = E - e0;                       // edges in this block
  if (eib > EPB) eib = EPB;
  int creg[16];
#pragma unroll
  for (int it = 0; it < 16; ++it) {
    int e = e0 + it * 256 + tid;
    creg[it] = (e < E) ? col[e] : -1;
  }
#pragma unroll
  for (int it = 0; it < 16; ++it) {
    if (creg[it] >= 0) atomicAdd(&lcnt[creg[it] >> NPB_SHIFT], 1);
  }
  __syncthreads();
  // reserve global runs (reads lcnt counts) + zero cursors
  for (int b = tid; b < MAXB; b += 256) {
    int c = (b < nb) ? lcnt[b] : 0;
    lbase[b] = (c > 0) ? atomicAdd(&gcur[b], c) + b * CAPB : b * CAPB;
    lcur[b] = 0;
  }
  // exclusive Blelloch scan over lcnt[0..511] -> lstart (in place)
  for (int d = 1; d < MAXB; d <<= 1) {
    __syncthreads();
    int idx = (tid + 1) * (d << 1) - 1;
    if (idx < MAXB) lcnt[idx] += lcnt[idx - d];
  }
  __syncthreads();
  if (tid == 0) lcnt[MAXB - 1] = 0;
  for (int d = MAXB >> 1; d >= 1; d >>= 1) {
    __syncthreads();
    int idx = (tid + 1) * (d << 1) - 1;
    if (idx < MAXB) {
      int t = lcnt[idx - d];
      lcnt[idx - d] = lcnt[idx];
      lcnt[idx] += t;
    }
  }
  __syncthreads();
  // scatter into LDS segments (lcnt now holds lstart)
#pragma unroll
  for (int it = 0; it < 16; ++it) {
    int e = e0 + it * 256 + tid;
    if (e < E) {
      int c = creg[it];
      int s = row[e];
      int b = c >> NPB_SHIFT;
      int lpos = atomicAdd(&lcur[b], 1);
      int gaddr = lbase[b] + lpos;
      int slot = lcnt[b] + lpos;
      eLDS[slot] = ((unsigned)s << NPB_SHIFT) | (unsigned)(c & (NPB - 1));
      aLDS[slot] = (gaddr < (b + 1) * CAPB) ? (unsigned)gaddr : 0xFFFFFFFFu;
    }
  }
  __syncthreads();
  // emission: slots [0, eib) are densely filled, sorted by global address
  for (int i = tid; i < eib; i += 256) {
    unsigned a = aLDS[i];
    if (a != 0xFFFFFFFFu) binned[a] = eLDS[i];
  }
}

// ---- phase B (1024 thr): per-bucket LDS ranks; L2-local scatter (uint4 index
// reads); self+pad8; fused prescale xh = f16(dinv*x) (float4 in / uint2 out) ----
__global__ __launch_bounds__(BBT) void k_binB(const unsigned int* __restrict__ binned,
                                              const int* __restrict__ gcur,
                                              int* __restrict__ counts,
                                              float* __restrict__ dinv,
                                              int* __restrict__ srcbuf,
                                              const float4* __restrict__ x4,
                                              unsigned* __restrict__ xh,
                                              int N) {
  __shared__ int cur[NPB];
  __shared__ float dl[NPB];
  int tid = threadIdx.x;
  int b = blockIdx.x;
  if (tid < NPB) cur[tid] = 0;
  __syncthreads();
  int cnt = gcur[b];
  if (cnt > CAPB) cnt = CAPB;
  const unsigned int* bp = binned + (size_t)b * CAPB;
  int nb0 = b << NPB_SHIFT;
#define BPROC(pv)                                                          \
  {                                                                        \
    int li_ = (int)((pv) & (NPB - 1));                                     \
    int r_ = atomicAdd(&cur[li_], 1);                                      \
    if (r_ < CAP - 1)                                                      \
      srcbuf[((size_t)(nb0 + li_) << 6) + r_] = (int)((pv) >> NPB_SHIFT);  \
  }
  int nv = cnt >> 2;  // full uint4 groups (CAPB%4==0 so bp is 16B-aligned)
  const uint4* bp4 = (const uint4*)bp;
  for (int i = tid; i < nv; i += BBT) {
    uint4 p = bp4[i];
    BPROC(p.x); BPROC(p.y); BPROC(p.z); BPROC(p.w);
  }
  for (int e = (nv << 2) + tid; e < cnt; e += BBT) BPROC(bp[e]);
#undef BPROC
  __syncthreads();
  if (tid < NPB) {
    int node = nb0 + tid;
    if (node < N) {
      int c = cur[tid];
      int mlen = (c < CAP - 1) ? c : (CAP - 1);
      int* myp = srcbuf + ((size_t)node << 6);
      myp[mlen] = node;                    // self-loop entry (operand prescaled)
      int cntp = (mlen + 1 + 7) & ~7;      // pad to multiple of 8
      for (int p2 = mlen + 1; p2 < cntp; ++p2) myp[p2] = N;  // sentinel zero row
      counts[node] = cntp;
      float d = rsqrtf((float)c + 1.0f);
      dinv[node] = d;
      dl[tid] = d;
    }
  }
  __syncthreads();
  // fused prescale: 256 nodes x 32 float4 = 8192 float4s, 1/thread/iter
  uint2* xh2 = (uint2*)xh;
#pragma unroll
  for (int it = 0; it < 8; ++it) {
    int idx = it * BBT + tid;  // 0..8191
    int ln = idx >> 5;         // 32 float4 per row
    if (nb0 + ln < N) {
      float4 v = x4[((size_t)nb0 << 5) + idx];
      float d = dl[ln];
      uint2 o;
      o.x = pkh2(v.x * d, v.y * d);
      o.y = pkh2(v.z * d, v.w * d);
      xh2[((size_t)nb0 << 5) + idx] = o;
    }
  }
}

// ---- hop: S[node] = sum over padded src list (incl self) of f16 rows.
// dwordx4 gathers: 16-lane subgroup g covers one edge; lane m owns 16B
// (8 f16 cols). Accumulate PACKED via v_pk_add_f16: 4 VALU per uint4.
// MODE 1: write f16(d^2*S) (stay pre-scaled). MODE 2: write f16(d*S). ----
#define PACC(v)                                   \
  A[0] += __builtin_bit_cast(h2v, (v).x);         \
  A[1] += __builtin_bit_cast(h2v, (v).y);         \
  A[2] += __builtin_bit_cast(h2v, (v).z);         \
  A[3] += __builtin_bit_cast(h2v, (v).w);

template <int MODE>
__global__ __launch_bounds__(256) void k_hop(
    const unsigned* __restrict__ hin, unsigned* __restrict__ hout,
    const int* __restrict__ srcbuf, const int* __restrict__ counts,
    const float* __restrict__ dinv, int n) {
  int wave = __builtin_amdgcn_readfirstlane((int)(threadIdx.x >> 6));
  int lane = threadIdx.x & 63;
  int node = blockIdx.x * 4 + wave;
  if (node >= n) return;
  int cntp = counts[node];  // multiple of 8, >= 8 (self always present)
  float di = dinv[node];
  int g = lane >> 4;
  int m = lane & 15;
  const uint4* h4 = (const uint4*)hin;
  const int* sp = srcbuf + ((size_t)node << 6);
  h2v A[4];
#pragma unroll
  for (int q = 0; q < 4; ++q) A[q] = (h2v)(_Float16)0;
  int e = 0;
  for (; e + 16 <= cntp; e += 16) {
    int s0 = sp[e + g];
    int s1 = sp[e + 4 + g];
    int s2 = sp[e + 8 + g];
    int s3 = sp[e + 12 + g];
    uint4 v0 = h4[((size_t)s0 << 4) + m];
    uint4 v1 = h4[((size_t)s1 << 4) + m];
    uint4 v2 = h4[((size_t)s2 << 4) + m];
    uint4 v3 = h4[((size_t)s3 << 4) + m];
    PACC(v0); PACC(v1); PACC(v2); PACC(v3);
  }
  if (e < cntp) {  // exactly 8 remain
    int s0 = sp[e + g];
    int s1 = sp[e + 4 + g];
    uint4 v0 = h4[((size_t)s0 << 4) + m];
    uint4 v1 = h4[((size_t)s1 << 4) + m];
    PACC(v0); PACC(v1);
  }
  // combine the 4 edge-subgroups (packed adds through shfl)
#pragma unroll
  for (int q = 0; q < 4; ++q) {
    A[q] += __builtin_bit_cast(h2v, __shfl_xor(__builtin_bit_cast(int, A[q]), 32));
    A[q] += __builtin_bit_cast(h2v, __shfl_xor(__builtin_bit_cast(int, A[q]), 16));
  }
  float s = (MODE == 1) ? di * di : di;
  if (g == 0) {
    uint4 o;
    o.x = pkh2((float)A[0][0] * s, (float)A[0][1] * s);
    o.y = pkh2((float)A[1][0] * s, (float)A[1][1] * s);
    o.z = pkh2((float)A[2][0] * s, (float)A[2][1] * s);
    o.w = pkh2((float)A[3][0] * s, (float)A[3][1] * s);
    *(uint4*)&hout[((size_t)node << 6) + (m << 2)] = o;  // 16 lanes x 16B = row
  }
}

// ---- out = h2h @ W^T + b via mfma_f32_16x16x32_f16.
// Wave = one 16-row tile. A frag: row=lane&15, k=(lane>>4)*8+i. W cvt to f16
// in LDS, per-row XOR swizzle -> conflict-free broadcast reads.
// C/D: col=lane&15, row=(lane>>4)*4+reg (dtype-independent). ----
__global__ __launch_bounds__(256) void k_gemm_mfma(
    const unsigned* __restrict__ h2h, const float* __restrict__ W,
    const float* __restrict__ bias, float* __restrict__ out, int n) {
  __shared__ _Float16 Wl[128 * 128];  // 32 KB
  int tid = threadIdx.x;
  const float4* Wg4 = (const float4*)W;
#pragma unroll
  for (int it = 0; it < 8; ++it) {
    int idx = tid + (it << 8);
    int c = idx >> 4;
    int j = idx & 15;
    float4 a = Wg4[c * 32 + j * 2];
    float4 bq = Wg4[c * 32 + j * 2 + 1];
    half8v s;
    s[0] = (_Float16)a.x;  s[1] = (_Float16)a.y;
    s[2] = (_Float16)a.z;  s[3] = (_Float16)a.w;
    s[4] = (_Float16)bq.x; s[5] = (_Float16)bq.y;
    s[6] = (_Float16)bq.z; s[7] = (_Float16)bq.w;
    int eo = (j << 3) ^ ((c & 7) << 3);
    *(half8v*)&Wl[(c << 7) + eo] = s;
  }
  __syncthreads();

  int wv = __builtin_amdgcn_readfirstlane((int)(tid >> 6));
  int lane = tid & 63;
  int tiles = (n + 15) >> 4;
  int tile = blockIdx.x * 4 + wv;
  if (tile >= tiles) return;
  int row0 = tile << 4;
  int r = lane & 15, g = lane >> 4;

  int arow = row0 + r;
  if (arow >= n) arow = n - 1;
  const _Float16* hrow = (const _Float16*)(h2h + ((size_t)arow << 6));
  half8v A0 = *(const half8v*)&hrow[g * 8];
  half8v A1 = *(const half8v*)&hrow[g * 8 + 32];
  half8v A2 = *(const half8v*)&hrow[g * 8 + 64];
  half8v A3 = *(const half8v*)&hrow[g * 8 + 96];

#pragma unroll
  for (int ct = 0; ct < 8; ++ct) {
    int c = (ct << 4) + r;
    int sw = (c & 7) << 3;
    const _Float16* wrow = &Wl[c << 7];
    half8v B0 = *(const half8v*)&wrow[(g * 8) ^ sw];
    half8v B1 = *(const half8v*)&wrow[(g * 8 + 32) ^ sw];
    half8v B2 = *(const half8v*)&wrow[(g * 8 + 64) ^ sw];
    half8v B3 = *(const half8v*)&wrow[(g * 8 + 96) ^ sw];
    f32x4 acc = {0.f, 0.f, 0.f, 0.f};
    acc = __builtin_amdgcn_mfma_f32_16x16x32_f16(A0, B0, acc, 0, 0, 0);
    acc = __builtin_amdgcn_mfma_f32_16x16x32_f16(A1, B1, acc, 0, 0, 0);
    acc = __builtin_amdgcn_mfma_f32_16x16x32_f16(A2, B2, acc, 0, 0, 0);
    acc = __builtin_amdgcn_mfma_f32_16x16x32_f16(A3, B3, acc, 0, 0, 0);
    float bb = bias[c];
#pragma unroll
    for (int q = 0; q < 4; ++q) {
      int rr = row0 + g * 4 + q;
      if (rr < n) out[(size_t)rr * 128 + c] = acc[q] + bb;
    }
  }
}

extern "C" void kernel_launch(void* const* d_in, const int* in_sizes, int n_in,
                              void* d_out, int out_size, void* d_ws, size_t ws_size,
                              hipStream_t stream) {
  const float* x = (const float*)d_in[0];
  const int* ei = (const int*)d_in[1];
  const float* W = (const float*)d_in[2];
  const float* b = (const float*)d_in[3];
  int N = in_sizes[0] / 128;
  int E = in_sizes[1] / 2;
  float* out = (float*)d_out;

  char* ws = (char*)d_ws;
  int* counts = (int*)ws;
  float* dinv = (float*)(ws + (512u << 10));
  int* gcur = (int*)(ws + (960u << 10));
  int* srcbuf = (int*)(ws + (1u << 20));
  unsigned* xh = (unsigned*)(ws + (27u << 20));
  unsigned* h2h = xh;  // xh dead after hop1; reuse for hop2 output
  unsigned* h1h = (unsigned*)(ws + (53u << 20));
  unsigned int* binned = (unsigned int*)(ws + (53u << 20));  // dead before hop1

  int nb = (N + NPB - 1) >> NPB_SHIFT;
  int blocksA = (E + EPB - 1) / EPB;
  int tiles = (N + 15) >> 4;

  hipMemsetAsync(gcur, 0, nb * sizeof(int), stream);
  k_binA<<<blocksA, 256, 0, stream>>>(ei, ei + E, gcur, binned, xh, h1h, E, nb, N);
  k_binB<<<nb, BBT, 0, stream>>>(binned, gcur, counts, dinv, srcbuf,
                                 (const float4*)x, xh, N);
  k_hop<1><<<(N + 3) / 4, 256, 0, stream>>>(xh, h1h, srcbuf, counts, dinv, N);
  k_hop<2><<<(N + 3) / 4, 256, 0, stream>>>(h1h, h2h, srcbuf, counts, dinv, N);
  k_gemm_mfma<<<(tiles + 3) / 4, 256, 0, stream>>>(h2h, W, b, out, N);
}